// Round 7
// baseline (215.279 us; speedup 1.0000x reference)
//
#include <hip/hip_runtime.h>

// MHA forward, B=2, S=2048, D=1024, H=16, K=64, fp32 in/out, bf16 MFMA internally.
// R7: GEMMs get the R5 treatment — BK=32 double-buffered LDS with vmcnt(N) prefetch
// (loads in flight across barriers). V-transpose fused into gemm_qkv epilogue
// (per-wave LDS transpose, coalesced writes) — transv kernel deleted. attn unchanged.

#define NH 16
#define KS 64
#define DM 1024
#define BB 2
#define SS 2048
#define NT (BB*SS)   // 4096 tokens
#define HKD 1024     // NH*KS
#define L2E 1.44269504088896340736f

typedef __attribute__((ext_vector_type(4))) float floatx4;
typedef __attribute__((ext_vector_type(8))) short short8;

__device__ __forceinline__ unsigned short f2b(float f) {
  unsigned u = __builtin_bit_cast(unsigned, f);
  u = (u + 0x7fffu + ((u >> 16) & 1u)) >> 16;
  return (unsigned short)u;
}

__device__ __forceinline__ floatx4 mfma16(short8 a, short8 b, floatx4 c) {
  return __builtin_amdgcn_mfma_f32_16x16x32_bf16(a, b, c, 0, 0, 0);
}

// async global->LDS, 16B per lane. LDS dest must be wave-uniform base + lane*16.
__device__ __forceinline__ void async16(const void* g, void* l) {
  __builtin_amdgcn_global_load_lds(
      (const __attribute__((address_space(1))) unsigned int*)g,
      (__attribute__((address_space(3))) unsigned int*)l, 16, 0, 0);
}

// ---------------- cast x (f32 -> bf16) ----------------
__global__ void cast_x_kernel(const float* __restrict__ x, unsigned short* __restrict__ xb) {
  int i = (blockIdx.x * 256 + threadIdx.x) * 4;
  float4 v = *(const float4*)(x + i);
  ushort4 o;
  o.x = f2b(v.x); o.y = f2b(v.y); o.z = f2b(v.z); o.w = f2b(v.w);
  *(ushort4*)(xb + i) = o;
}

// ------------- transpose + cast W (1024x1024 f32 -> Wt[n][k] bf16) -------------
__global__ void transw_kernel(const float* __restrict__ Wq, const float* __restrict__ Wk,
                              const float* __restrict__ Wv, const float* __restrict__ Wo,
                              unsigned short* __restrict__ wqt, unsigned short* __restrict__ wkt,
                              unsigned short* __restrict__ wvt, unsigned short* __restrict__ wot) {
  const float* W; unsigned short* Wt;
  if (blockIdx.z == 0)      { W = Wq; Wt = wqt; }
  else if (blockIdx.z == 1) { W = Wk; Wt = wkt; }
  else if (blockIdx.z == 2) { W = Wv; Wt = wvt; }
  else                      { W = Wo; Wt = wot; }
  __shared__ __align__(16) unsigned short tile[64][80];
  int k0 = blockIdx.x * 64, n0 = blockIdx.y * 64;
  int t = threadIdx.x;
  int c0 = (t & 15) * 4, r = t >> 4;
  #pragma unroll
  for (int p = 0; p < 4; ++p) {
    int rr = r + p * 16;
    float4 v = *(const float4*)(W + (k0 + rr) * DM + n0 + c0);
    tile[c0 + 0][rr] = f2b(v.x);
    tile[c0 + 1][rr] = f2b(v.y);
    tile[c0 + 2][rr] = f2b(v.z);
    tile[c0 + 3][rr] = f2b(v.w);
  }
  __syncthreads();
  int cc0 = (t & 7) * 8, rn = t >> 3;
  #pragma unroll
  for (int p = 0; p < 2; ++p) {
    int nn = rn + p * 32;
    *(short8*)(Wt + (n0 + nn) * DM + k0 + cc0) = *(const short8*)(&tile[nn][cc0]);
  }
}

// ---- QKV GEMM: 128x128 tile, 4 waves, BK=32 dbuf + vmcnt(4) prefetch ----
// z==2 (V): epilogue transposes per-wave 64x64 C tiles through LDS and writes
// directly into vt (B,H,64,S) with coalesced 128B rows.
__global__ __launch_bounds__(256) void gemm_qkv_kernel(
    const unsigned short* __restrict__ xb,
    const unsigned short* __restrict__ wqt, const unsigned short* __restrict__ wkt,
    const unsigned short* __restrict__ wvt,
    const float* __restrict__ bq, const float* __restrict__ bk, const float* __restrict__ bv,
    unsigned short* __restrict__ qb, unsigned short* __restrict__ kbuf,
    unsigned short* __restrict__ vt) {
  // union: dbuf tiles (16384 elems = 32 KB) | V-transpose 4 x 4608 elems (36 KB)
  __shared__ __align__(16) unsigned short smem[18432];
  const unsigned short* Bt; const float* bias; float scale; int zid = blockIdx.z;
  if (zid == 0)      { Bt = wqt; bias = bq; scale = 0.125f * L2E; }
  else if (zid == 1) { Bt = wkt; bias = bk; scale = 1.0f; }
  else               { Bt = wvt; bias = bv; scale = 1.0f; }
  int m0 = blockIdx.x * 128, n0 = blockIdx.y * 128;
  int t = threadIdx.x, w = t >> 6, lane = t & 63, cl = lane & 15, quad = lane >> 4;
  int wr = (w >> 1) * 64, wc = (w & 1) * 64;
  floatx4 acc[4][4];
  #pragma unroll
  for (int i = 0; i < 4; ++i)
    #pragma unroll
    for (int j = 0; j < 4; ++j)
      acc[i][j] = floatx4{0.f, 0.f, 0.f, 0.f};

  auto stage = [&](int kc, int buf) {
    #pragma unroll
    for (int i = 0; i < 2; ++i) {
      int c = i * 256 + t;                       // 0..511
      int row = c >> 2, col = (c & 3) ^ (row & 3);
      async16(xb + (m0 + row) * DM + kc * 32 + col * 8, &smem[buf * 4096 + c * 8]);
      async16(Bt + (n0 + row) * DM + kc * 32 + col * 8, &smem[8192 + buf * 4096 + c * 8]);
    }
  };
  stage(0, 0);
  stage(1, 1);

  for (int kc = 0; kc < DM / 32; ++kc) {
    int cur = kc & 1;
    if (kc < DM / 32 - 1) asm volatile("s_waitcnt vmcnt(4)" ::: "memory");
    else                  asm volatile("s_waitcnt vmcnt(0)" ::: "memory");
    __syncthreads();
    const unsigned short* Ac = &smem[cur * 4096];
    const unsigned short* Bc = &smem[8192 + cur * 4096];
    short8 a[4], b[4];
    #pragma unroll
    for (int i = 0; i < 4; ++i)
      a[i] = *(const short8*)&Ac[(wr + i * 16 + cl) * 32 + ((quad ^ (cl & 3)) * 8)];
    #pragma unroll
    for (int j = 0; j < 4; ++j)
      b[j] = *(const short8*)&Bc[(wc + j * 16 + cl) * 32 + ((quad ^ (cl & 3)) * 8)];
    #pragma unroll
    for (int i = 0; i < 4; ++i)
      #pragma unroll
      for (int j = 0; j < 4; ++j)
        acc[i][j] = mfma16(a[i], b[j], acc[i][j]);
    __syncthreads();
    if (kc + 2 < DM / 32) stage(kc + 2, cur);
  }
  __syncthreads(); // all waves done with dbuf LDS before epilogue reuse

  int h = (n0 + wc) >> 6;
  if (zid < 2) {
    unsigned short* dst = (zid == 0) ? qb : kbuf;
    #pragma unroll
    for (int j = 0; j < 4; ++j) {
      float bj = bias[n0 + wc + j * 16 + cl];
      int kd = j * 16 + cl;
      #pragma unroll
      for (int i = 0; i < 4; ++i)
        #pragma unroll
        for (int r = 0; r < 4; ++r) {
          int token = m0 + wr + i * 16 + quad * 4 + r;
          int bz = token >> 11, s = token & (SS - 1);
          float val = (acc[i][j][r] + bj) * scale;
          dst[(((bz * NH + h) * SS + s) << 6) + kd] = f2b(val);
        }
    }
  } else {
    // V: per-wave 64x64 transpose via LDS (stride 72), coalesced write to vt
    unsigned short* tr = &smem[w * 4608];
    #pragma unroll
    for (int j = 0; j < 4; ++j) {
      float bj = bias[n0 + wc + j * 16 + cl];
      #pragma unroll
      for (int i = 0; i < 4; ++i) {
        unsigned short b0 = f2b(acc[i][j][0] + bj), b1 = f2b(acc[i][j][1] + bj);
        unsigned short b2 = f2b(acc[i][j][2] + bj), b3 = f2b(acc[i][j][3] + bj);
        uint2 pk;
        pk.x = (unsigned)b0 | ((unsigned)b1 << 16);
        pk.y = (unsigned)b2 | ((unsigned)b3 << 16);
        *(uint2*)&tr[(j * 16 + cl) * 72 + i * 16 + quad * 4] = pk;
      }
    }
    asm volatile("s_waitcnt lgkmcnt(0)" ::: "memory"); // own-wave writes only
    int tokbase = m0 + wr;
    int bz = tokbase >> 11, s0 = tokbase & (SS - 1);
    unsigned short* vdst = vt + (((bz * NH + h) * KS) * SS) + s0;
    #pragma unroll
    for (int p = 0; p < 8; ++p) {
      int row = p * 8 + (lane >> 3);   // kd 0..63
      int tk = (lane & 7) * 8;         // token offset
      short8 vv = *(const short8*)&tr[row * 72 + tk];
      *(short8*)(vdst + row * SS + tk) = vv;
    }
  }
}

// ---- attention: 4 waves x 16 q-rows, S^T/O^T orientation, dbuf K/V, vmcnt(4) ----
__global__ __launch_bounds__(256) void attn_kernel(
    const unsigned short* __restrict__ Q, const unsigned short* __restrict__ Kb,
    const unsigned short* __restrict__ Vt, unsigned short* __restrict__ AO) {
  __shared__ __align__(16) unsigned short Ks[2][4096], Vs[2][4096]; // 64x64 swizzled dbuf (32 KB)
  __shared__ __align__(16) unsigned short Ps[4][1024];              // per-wave P^T, swizzled (8 KB)
  int t = threadIdx.x, w = t >> 6, lane = t & 63, cl = lane & 15, quad = lane >> 4;
  int clm = cl & 7;
  int h = blockIdx.y, bz = blockIdx.z, bh = bz * NH + h;
  int q0 = blockIdx.x * 64 + w * 16;
  const unsigned short* Qp = Q + (bh * SS + q0) * KS;
  const unsigned short* Kp = Kb + bh * SS * KS;
  const unsigned short* Vp = Vt + bh * KS * SS;
  unsigned short* p_w = Ps[w];

  short8 qa[2];
  #pragma unroll
  for (int c = 0; c < 2; ++c)
    qa[c] = *(const short8*)(Qp + cl * KS + c * 32 + quad * 8);

  float l = 0.f;
  floatx4 oa[4];
  #pragma unroll
  for (int j = 0; j < 4; ++j) oa[j] = floatx4{0.f, 0.f, 0.f, 0.f};

  auto stage = [&](int tile, int buf) {
    const unsigned short* kp = Kp + (tile * 64) * KS;
    #pragma unroll
    for (int i = 0; i < 2; ++i) {
      int c = i * 256 + t;
      int row = c >> 3, col8 = (c & 7) ^ (row & 7);
      async16(kp + row * KS + col8 * 8, &Ks[buf][c * 8]);
    }
    #pragma unroll
    for (int i = 0; i < 2; ++i) {
      int c = i * 256 + t;
      int d = c >> 3, col8 = (c & 7) ^ (d & 7);
      async16(Vp + d * SS + tile * 64 + col8 * 8, &Vs[buf][c * 8]);
    }
  };
  stage(0, 0);
  stage(1, 1);

  const int NTILES = SS / 64;
  for (int it = 0; it < NTILES; ++it) {
    int cur = it & 1;
    if (it < NTILES - 1) asm volatile("s_waitcnt vmcnt(4)" ::: "memory");
    else                 asm volatile("s_waitcnt vmcnt(0)" ::: "memory");
    __syncthreads();

    floatx4 s[4];
    #pragma unroll
    for (int kt = 0; kt < 4; ++kt) {
      short8 kb0 = *(const short8*)&Ks[cur][(kt * 16 + cl) * 64 + ((quad ^ clm) * 8)];
      short8 kb1 = *(const short8*)&Ks[cur][(kt * 16 + cl) * 64 + (((4 + quad) ^ clm) * 8)];
      floatx4 z = {0.f, 0.f, 0.f, 0.f};
      s[kt] = mfma16(kb1, qa[1], mfma16(kb0, qa[0], z));
    }
    #pragma unroll
    for (int kt = 0; kt < 4; ++kt) {
      unsigned u[4];
      #pragma unroll
      for (int r = 0; r < 4; ++r) {
        float p = __builtin_amdgcn_exp2f(s[kt][r]);
        u[r] = __builtin_bit_cast(unsigned, p) & 0xffff0000u;
        l += __builtin_bit_cast(float, u[r]);
      }
      uint2 pk;
      pk.x = (u[0] >> 16) | u[1];
      pk.y = (u[2] >> 16) | u[3];
      int off = cl * 64 + (((kt * 2 + (quad >> 1)) ^ clm) * 8) + (quad & 1) * 4;
      *(uint2*)(p_w + off) = pk;
    }
    asm volatile("s_waitcnt lgkmcnt(0)" ::: "memory");
    short8 pa[2];
    #pragma unroll
    for (int c = 0; c < 2; ++c)
      pa[c] = *(const short8*)(p_w + cl * 64 + (((c * 4 + quad) ^ clm) * 8));
    #pragma unroll
    for (int j = 0; j < 4; ++j) {
      short8 vb0 = *(const short8*)&Vs[cur][(j * 16 + cl) * 64 + ((quad ^ clm) * 8)];
      short8 vb1 = *(const short8*)&Vs[cur][(j * 16 + cl) * 64 + (((4 + quad) ^ clm) * 8)];
      oa[j] = mfma16(vb1, pa[1], mfma16(vb0, pa[0], oa[j]));
    }
    __syncthreads();
    if (it + 2 < NTILES) stage(it + 2, cur);
  }

  l += __shfl_xor(l, 16);
  l += __shfl_xor(l, 32);
  float inv = 1.0f / l;
  unsigned short* aop = AO + (bz * SS + q0 + cl) * DM + h * KS + quad * 4;
  #pragma unroll
  for (int j = 0; j < 4; ++j) {
    unsigned short b0 = f2b(oa[j][0] * inv), b1 = f2b(oa[j][1] * inv);
    unsigned short b2 = f2b(oa[j][2] * inv), b3 = f2b(oa[j][3] * inv);
    uint2 pk;
    pk.x = (unsigned)b0 | ((unsigned)b1 << 16);
    pk.y = (unsigned)b2 | ((unsigned)b3 << 16);
    *(uint2*)(aop + j * 16) = pk;
  }
}

// ---- output GEMM: 128x64 tile, 2 waves, BK=32 dbuf + vmcnt(6), f32 out + bias ----
__global__ __launch_bounds__(128) void gemm_out_kernel(
    const unsigned short* __restrict__ ao, const unsigned short* __restrict__ wot,
    const float* __restrict__ bo, float* __restrict__ out) {
  __shared__ __align__(16) unsigned short As[2][4096], Bs[2][2048]; // 24 KB
  int m0 = blockIdx.x * 128, n0 = blockIdx.y * 64;
  int t = threadIdx.x, w = t >> 6, lane = t & 63, cl = lane & 15, quad = lane >> 4;
  int wr = w * 64;
  floatx4 acc[4][4];
  #pragma unroll
  for (int i = 0; i < 4; ++i)
    #pragma unroll
    for (int j = 0; j < 4; ++j)
      acc[i][j] = floatx4{0.f, 0.f, 0.f, 0.f};

  auto stage = [&](int kc, int buf) {
    #pragma unroll
    for (int i = 0; i < 4; ++i) {
      int c = i * 128 + t;                       // 0..511
      int row = c >> 2, col = (c & 3) ^ (row & 3);
      async16(ao + (m0 + row) * HKD + kc * 32 + col * 8, &As[buf][c * 8]);
    }
    #pragma unroll
    for (int i = 0; i < 2; ++i) {
      int c = i * 128 + t;                       // 0..255
      int row = c >> 2, col = (c & 3) ^ (row & 3);
      async16(wot + (n0 + row) * HKD + kc * 32 + col * 8, &Bs[buf][c * 8]);
    }
  };
  stage(0, 0);
  stage(1, 1);

  for (int kc = 0; kc < HKD / 32; ++kc) {
    int cur = kc & 1;
    if (kc < HKD / 32 - 1) asm volatile("s_waitcnt vmcnt(6)" ::: "memory");
    else                   asm volatile("s_waitcnt vmcnt(0)" ::: "memory");
    __syncthreads();
    short8 a[4], b[4];
    #pragma unroll
    for (int i = 0; i < 4; ++i)
      a[i] = *(const short8*)&As[cur][(wr + i * 16 + cl) * 32 + ((quad ^ (cl & 3)) * 8)];
    #pragma unroll
    for (int j = 0; j < 4; ++j)
      b[j] = *(const short8*)&Bs[cur][(j * 16 + cl) * 32 + ((quad ^ (cl & 3)) * 8)];
    #pragma unroll
    for (int i = 0; i < 4; ++i)
      #pragma unroll
      for (int j = 0; j < 4; ++j)
        acc[i][j] = mfma16(a[i], b[j], acc[i][j]);
    __syncthreads();
    if (kc + 2 < HKD / 32) stage(kc + 2, cur);
  }
  #pragma unroll
  for (int j = 0; j < 4; ++j) {
    float bj = bo[n0 + j * 16 + cl];
    #pragma unroll
    for (int i = 0; i < 4; ++i)
      #pragma unroll
      for (int r = 0; r < 4; ++r) {
        int token = m0 + wr + i * 16 + quad * 4 + r;
        out[token * DM + n0 + j * 16 + cl] = acc[i][j][r] + bj;
      }
  }
}

extern "C" void kernel_launch(void* const* d_in, const int* in_sizes, int n_in,
                              void* d_out, int out_size, void* d_ws, size_t ws_size,
                              hipStream_t stream) {
  const float* x  = (const float*)d_in[0];
  const float* Wq = (const float*)d_in[1];
  const float* bq = (const float*)d_in[2];
  const float* Wk = (const float*)d_in[3];
  const float* bk = (const float*)d_in[4];
  const float* Wv = (const float*)d_in[5];
  const float* bv = (const float*)d_in[6];
  const float* Wo = (const float*)d_in[7];
  const float* bo = (const float*)d_in[8];
  float* out = (float*)d_out;
  char* ws = (char*)d_ws;
  unsigned short* xb  = (unsigned short*)(ws);                       // 8 MiB
  unsigned short* wqt = (unsigned short*)(ws + (8ull  << 20));       // 2 MiB
  unsigned short* wkt = (unsigned short*)(ws + (10ull << 20));       // 2 MiB
  unsigned short* wvt = (unsigned short*)(ws + (12ull << 20));       // 2 MiB
  unsigned short* wot = (unsigned short*)(ws + (14ull << 20));       // 2 MiB
  unsigned short* qb  = (unsigned short*)(ws + (16ull << 20));       // 8 MiB
  unsigned short* kbf = (unsigned short*)(ws + (24ull << 20));       // 8 MiB
  unsigned short* vt  = (unsigned short*)(ws + (40ull << 20));       // 8 MiB
  unsigned short* ao  = (unsigned short*)(ws + (48ull << 20));       // 8 MiB

  hipLaunchKernelGGL(cast_x_kernel, dim3(NT * DM / 1024), dim3(256), 0, stream, x, xb);
  hipLaunchKernelGGL(transw_kernel, dim3(16, 16, 4), dim3(256), 0, stream,
                     Wq, Wk, Wv, Wo, wqt, wkt, wvt, wot);
  hipLaunchKernelGGL(gemm_qkv_kernel, dim3(NT / 128, HKD / 128, 3), dim3(256), 0, stream,
                     xb, wqt, wkt, wvt, bq, bk, bv, qb, kbf, vt);
  hipLaunchKernelGGL(attn_kernel, dim3(SS / 64, NH, BB), dim3(256), 0, stream, qb, kbf, vt, ao);
  hipLaunchKernelGGL(gemm_out_kernel, dim3(NT / 128, DM / 64), dim3(128), 0, stream, ao, wot, bo, out);
}

// Round 8
// 215.075 us; speedup vs baseline: 1.0009x; 1.0009x over previous
//
#include <hip/hip_runtime.h>

// MHA forward, B=2, S=2048, D=1024, H=16, K=64, fp32 in/out, bf16 MFMA internally.
// R8: attn inner-loop VALU cut — row-sum l computed by ones-vector MFMA (matrix pipe,
// consistent with PV by construction), bf16 pack via v_perm_b32 (1 inst). cast_x and
// transw merged into one prep_kernel (one fewer launch). GEMMs unchanged from R7.

#define NH 16
#define KS 64
#define DM 1024
#define BB 2
#define SS 2048
#define NT (BB*SS)   // 4096 tokens
#define HKD 1024     // NH*KS
#define L2E 1.44269504088896340736f

typedef __attribute__((ext_vector_type(4))) float floatx4;
typedef __attribute__((ext_vector_type(8))) short short8;

__device__ __forceinline__ unsigned short f2b(float f) {
  unsigned u = __builtin_bit_cast(unsigned, f);
  u = (u + 0x7fffu + ((u >> 16) & 1u)) >> 16;
  return (unsigned short)u;
}

__device__ __forceinline__ floatx4 mfma16(short8 a, short8 b, floatx4 c) {
  return __builtin_amdgcn_mfma_f32_16x16x32_bf16(a, b, c, 0, 0, 0);
}

// async global->LDS, 16B per lane. LDS dest must be wave-uniform base + lane*16.
__device__ __forceinline__ void async16(const void* g, void* l) {
  __builtin_amdgcn_global_load_lds(
      (const __attribute__((address_space(1))) unsigned int*)g,
      (__attribute__((address_space(3))) unsigned int*)l, 16, 0, 0);
}

// ------ prep: cast x (f32->bf16) + transpose+cast all W, one launch ------
__global__ __launch_bounds__(256) void prep_kernel(
    const float* __restrict__ x,
    const float* __restrict__ Wq, const float* __restrict__ Wk,
    const float* __restrict__ Wv, const float* __restrict__ Wo,
    unsigned short* __restrict__ xb,
    unsigned short* __restrict__ wqt, unsigned short* __restrict__ wkt,
    unsigned short* __restrict__ wvt, unsigned short* __restrict__ wot) {
  int bid = blockIdx.x;
  if (bid < NT * DM / 1024) {
    int i = (bid * 256 + threadIdx.x) * 4;
    float4 v = *(const float4*)(x + i);
    ushort4 o;
    o.x = f2b(v.x); o.y = f2b(v.y); o.z = f2b(v.z); o.w = f2b(v.w);
    *(ushort4*)(xb + i) = o;
    return;
  }
  int b2 = bid - NT * DM / 1024;
  int z = b2 >> 8;
  const float* W; unsigned short* Wt;
  if (z == 0)      { W = Wq; Wt = wqt; }
  else if (z == 1) { W = Wk; Wt = wkt; }
  else if (z == 2) { W = Wv; Wt = wvt; }
  else             { W = Wo; Wt = wot; }
  __shared__ __align__(16) unsigned short tile[64][80];
  int k0 = (b2 & 15) * 64, n0 = ((b2 >> 4) & 15) * 64;
  int t = threadIdx.x;
  int c0 = (t & 15) * 4, r = t >> 4;
  #pragma unroll
  for (int p = 0; p < 4; ++p) {
    int rr = r + p * 16;
    float4 v = *(const float4*)(W + (k0 + rr) * DM + n0 + c0);
    tile[c0 + 0][rr] = f2b(v.x);
    tile[c0 + 1][rr] = f2b(v.y);
    tile[c0 + 2][rr] = f2b(v.z);
    tile[c0 + 3][rr] = f2b(v.w);
  }
  __syncthreads();
  int cc0 = (t & 7) * 8, rn = t >> 3;
  #pragma unroll
  for (int p = 0; p < 2; ++p) {
    int nn = rn + p * 32;
    *(short8*)(Wt + (n0 + nn) * DM + k0 + cc0) = *(const short8*)(&tile[nn][cc0]);
  }
}

// ---- QKV GEMM: 128x128 tile, 4 waves, BK=32 dbuf + vmcnt(4) prefetch ----
// z==2 (V): epilogue transposes per-wave 64x64 C tiles through LDS and writes
// directly into vt (B,H,64,S) with coalesced 128B rows.
__global__ __launch_bounds__(256) void gemm_qkv_kernel(
    const unsigned short* __restrict__ xb,
    const unsigned short* __restrict__ wqt, const unsigned short* __restrict__ wkt,
    const unsigned short* __restrict__ wvt,
    const float* __restrict__ bq, const float* __restrict__ bk, const float* __restrict__ bv,
    unsigned short* __restrict__ qb, unsigned short* __restrict__ kbuf,
    unsigned short* __restrict__ vt) {
  __shared__ __align__(16) unsigned short smem[18432];
  const unsigned short* Bt; const float* bias; float scale; int zid = blockIdx.z;
  if (zid == 0)      { Bt = wqt; bias = bq; scale = 0.125f * L2E; }
  else if (zid == 1) { Bt = wkt; bias = bk; scale = 1.0f; }
  else               { Bt = wvt; bias = bv; scale = 1.0f; }
  int m0 = blockIdx.x * 128, n0 = blockIdx.y * 128;
  int t = threadIdx.x, w = t >> 6, lane = t & 63, cl = lane & 15, quad = lane >> 4;
  int wr = (w >> 1) * 64, wc = (w & 1) * 64;
  floatx4 acc[4][4];
  #pragma unroll
  for (int i = 0; i < 4; ++i)
    #pragma unroll
    for (int j = 0; j < 4; ++j)
      acc[i][j] = floatx4{0.f, 0.f, 0.f, 0.f};

  auto stage = [&](int kc, int buf) {
    #pragma unroll
    for (int i = 0; i < 2; ++i) {
      int c = i * 256 + t;
      int row = c >> 2, col = (c & 3) ^ (row & 3);
      async16(xb + (m0 + row) * DM + kc * 32 + col * 8, &smem[buf * 4096 + c * 8]);
      async16(Bt + (n0 + row) * DM + kc * 32 + col * 8, &smem[8192 + buf * 4096 + c * 8]);
    }
  };
  stage(0, 0);
  stage(1, 1);

  for (int kc = 0; kc < DM / 32; ++kc) {
    int cur = kc & 1;
    if (kc < DM / 32 - 1) asm volatile("s_waitcnt vmcnt(4)" ::: "memory");
    else                  asm volatile("s_waitcnt vmcnt(0)" ::: "memory");
    __syncthreads();
    const unsigned short* Ac = &smem[cur * 4096];
    const unsigned short* Bc = &smem[8192 + cur * 4096];
    short8 a[4], b[4];
    #pragma unroll
    for (int i = 0; i < 4; ++i)
      a[i] = *(const short8*)&Ac[(wr + i * 16 + cl) * 32 + ((quad ^ (cl & 3)) * 8)];
    #pragma unroll
    for (int j = 0; j < 4; ++j)
      b[j] = *(const short8*)&Bc[(wc + j * 16 + cl) * 32 + ((quad ^ (cl & 3)) * 8)];
    #pragma unroll
    for (int i = 0; i < 4; ++i)
      #pragma unroll
      for (int j = 0; j < 4; ++j)
        acc[i][j] = mfma16(a[i], b[j], acc[i][j]);
    __syncthreads();
    if (kc + 2 < DM / 32) stage(kc + 2, cur);
  }
  __syncthreads();

  int h = (n0 + wc) >> 6;
  if (zid < 2) {
    unsigned short* dst = (zid == 0) ? qb : kbuf;
    #pragma unroll
    for (int j = 0; j < 4; ++j) {
      float bj = bias[n0 + wc + j * 16 + cl];
      int kd = j * 16 + cl;
      #pragma unroll
      for (int i = 0; i < 4; ++i)
        #pragma unroll
        for (int r = 0; r < 4; ++r) {
          int token = m0 + wr + i * 16 + quad * 4 + r;
          int bz = token >> 11, s = token & (SS - 1);
          float val = (acc[i][j][r] + bj) * scale;
          dst[(((bz * NH + h) * SS + s) << 6) + kd] = f2b(val);
        }
    }
  } else {
    unsigned short* tr = &smem[w * 4608];
    #pragma unroll
    for (int j = 0; j < 4; ++j) {
      float bj = bias[n0 + wc + j * 16 + cl];
      #pragma unroll
      for (int i = 0; i < 4; ++i) {
        unsigned short b0 = f2b(acc[i][j][0] + bj), b1 = f2b(acc[i][j][1] + bj);
        unsigned short b2 = f2b(acc[i][j][2] + bj), b3 = f2b(acc[i][j][3] + bj);
        uint2 pk;
        pk.x = (unsigned)b0 | ((unsigned)b1 << 16);
        pk.y = (unsigned)b2 | ((unsigned)b3 << 16);
        *(uint2*)&tr[(j * 16 + cl) * 72 + i * 16 + quad * 4] = pk;
      }
    }
    asm volatile("s_waitcnt lgkmcnt(0)" ::: "memory");
    int tokbase = m0 + wr;
    int bz = tokbase >> 11, s0 = tokbase & (SS - 1);
    unsigned short* vdst = vt + (((bz * NH + h) * KS) * SS) + s0;
    #pragma unroll
    for (int p = 0; p < 8; ++p) {
      int row = p * 8 + (lane >> 3);
      int tk = (lane & 7) * 8;
      short8 vv = *(const short8*)&tr[row * 72 + tk];
      *(short8*)(vdst + row * SS + tk) = vv;
    }
  }
}

// ---- attention: 4 waves x 16 q-rows, S^T/O^T orientation, dbuf K/V, vmcnt(4) ----
// l computed by ones-MFMA over the SAME P^T fragments used for PV (exactly
// consistent, no VALU adds, no final shuffles). Pack via v_perm_b32.
__global__ __launch_bounds__(256) void attn_kernel(
    const unsigned short* __restrict__ Q, const unsigned short* __restrict__ Kb,
    const unsigned short* __restrict__ Vt, unsigned short* __restrict__ AO) {
  __shared__ __align__(16) unsigned short Ks[2][4096], Vs[2][4096]; // 64x64 swizzled dbuf
  __shared__ __align__(16) unsigned short Ps[4][1024];              // per-wave P^T, swizzled
  int t = threadIdx.x, w = t >> 6, lane = t & 63, cl = lane & 15, quad = lane >> 4;
  int clm = cl & 7;
  int h = blockIdx.y, bz = blockIdx.z, bh = bz * NH + h;
  int q0 = blockIdx.x * 64 + w * 16;
  const unsigned short* Qp = Q + (bh * SS + q0) * KS;
  const unsigned short* Kp = Kb + bh * SS * KS;
  const unsigned short* Vp = Vt + bh * KS * SS;
  unsigned short* p_w = Ps[w];

  short8 qa[2];
  #pragma unroll
  for (int c = 0; c < 2; ++c)
    qa[c] = *(const short8*)(Qp + cl * KS + c * 32 + quad * 8);

  short8 ones;
  #pragma unroll
  for (int j = 0; j < 8; ++j) ones[j] = (short)0x3f80; // bf16 1.0

  floatx4 lacc = {0.f, 0.f, 0.f, 0.f};
  floatx4 oa[4];
  #pragma unroll
  for (int j = 0; j < 4; ++j) oa[j] = floatx4{0.f, 0.f, 0.f, 0.f};

  auto stage = [&](int tile, int buf) {
    const unsigned short* kp = Kp + (tile * 64) * KS;
    #pragma unroll
    for (int i = 0; i < 2; ++i) {
      int c = i * 256 + t;
      int row = c >> 3, col8 = (c & 7) ^ (row & 7);
      async16(kp + row * KS + col8 * 8, &Ks[buf][c * 8]);
    }
    #pragma unroll
    for (int i = 0; i < 2; ++i) {
      int c = i * 256 + t;
      int d = c >> 3, col8 = (c & 7) ^ (d & 7);
      async16(Vp + d * SS + tile * 64 + col8 * 8, &Vs[buf][c * 8]);
    }
  };
  stage(0, 0);
  stage(1, 1);

  const int NTILES = SS / 64;
  for (int it = 0; it < NTILES; ++it) {
    int cur = it & 1;
    if (it < NTILES - 1) asm volatile("s_waitcnt vmcnt(4)" ::: "memory");
    else                 asm volatile("s_waitcnt vmcnt(0)" ::: "memory");
    __syncthreads();

    floatx4 s[4];
    #pragma unroll
    for (int kt = 0; kt < 4; ++kt) {
      short8 kb0 = *(const short8*)&Ks[cur][(kt * 16 + cl) * 64 + ((quad ^ clm) * 8)];
      short8 kb1 = *(const short8*)&Ks[cur][(kt * 16 + cl) * 64 + (((4 + quad) ^ clm) * 8)];
      floatx4 z = {0.f, 0.f, 0.f, 0.f};
      s[kt] = mfma16(kb1, qa[1], mfma16(kb0, qa[0], z));
    }
    // exp2 + truncate-pack via v_perm (l comes from MFMA on these same bits)
    #pragma unroll
    for (int kt = 0; kt < 4; ++kt) {
      unsigned u[4];
      #pragma unroll
      for (int r = 0; r < 4; ++r)
        u[r] = __builtin_bit_cast(unsigned, __builtin_amdgcn_exp2f(s[kt][r]));
      uint2 pk;
      pk.x = __builtin_amdgcn_perm(u[1], u[0], 0x07060302);
      pk.y = __builtin_amdgcn_perm(u[3], u[2], 0x07060302);
      int off = cl * 64 + (((kt * 2 + (quad >> 1)) ^ clm) * 8) + (quad & 1) * 4;
      *(uint2*)(p_w + off) = pk;
    }
    asm volatile("s_waitcnt lgkmcnt(0)" ::: "memory");
    short8 pa[2];
    #pragma unroll
    for (int c = 0; c < 2; ++c)
      pa[c] = *(const short8*)(p_w + cl * 64 + (((c * 4 + quad) ^ clm) * 8));
    lacc = mfma16(ones, pa[1], mfma16(ones, pa[0], lacc)); // l row-sums (matrix pipe)
    #pragma unroll
    for (int j = 0; j < 4; ++j) {
      short8 vb0 = *(const short8*)&Vs[cur][(j * 16 + cl) * 64 + ((quad ^ clm) * 8)];
      short8 vb1 = *(const short8*)&Vs[cur][(j * 16 + cl) * 64 + (((4 + quad) ^ clm) * 8)];
      oa[j] = mfma16(vb1, pa[1], mfma16(vb0, pa[0], oa[j]));
    }
    __syncthreads();
    if (it + 2 < NTILES) stage(it + 2, cur);
  }

  // lacc: every reg of every quad holds l for q=cl — no cross-lane reduction needed
  float inv = 1.0f / lacc[0];
  unsigned short* aop = AO + (bz * SS + q0 + cl) * DM + h * KS + quad * 4;
  #pragma unroll
  for (int j = 0; j < 4; ++j) {
    unsigned short b0 = f2b(oa[j][0] * inv), b1 = f2b(oa[j][1] * inv);
    unsigned short b2 = f2b(oa[j][2] * inv), b3 = f2b(oa[j][3] * inv);
    uint2 pk;
    pk.x = (unsigned)b0 | ((unsigned)b1 << 16);
    pk.y = (unsigned)b2 | ((unsigned)b3 << 16);
    *(uint2*)(aop + j * 16) = pk;
  }
}

// ---- output GEMM: 128x64 tile, 2 waves, BK=32 dbuf + vmcnt(6), f32 out + bias ----
__global__ __launch_bounds__(128) void gemm_out_kernel(
    const unsigned short* __restrict__ ao, const unsigned short* __restrict__ wot,
    const float* __restrict__ bo, float* __restrict__ out) {
  __shared__ __align__(16) unsigned short As[2][4096], Bs[2][2048];
  int m0 = blockIdx.x * 128, n0 = blockIdx.y * 64;
  int t = threadIdx.x, w = t >> 6, lane = t & 63, cl = lane & 15, quad = lane >> 4;
  int wr = w * 64;
  floatx4 acc[4][4];
  #pragma unroll
  for (int i = 0; i < 4; ++i)
    #pragma unroll
    for (int j = 0; j < 4; ++j)
      acc[i][j] = floatx4{0.f, 0.f, 0.f, 0.f};

  auto stage = [&](int kc, int buf) {
    #pragma unroll
    for (int i = 0; i < 4; ++i) {
      int c = i * 128 + t;
      int row = c >> 2, col = (c & 3) ^ (row & 3);
      async16(ao + (m0 + row) * HKD + kc * 32 + col * 8, &As[buf][c * 8]);
    }
    #pragma unroll
    for (int i = 0; i < 2; ++i) {
      int c = i * 128 + t;
      int row = c >> 2, col = (c & 3) ^ (row & 3);
      async16(wot + (n0 + row) * HKD + kc * 32 + col * 8, &Bs[buf][c * 8]);
    }
  };
  stage(0, 0);
  stage(1, 1);

  for (int kc = 0; kc < HKD / 32; ++kc) {
    int cur = kc & 1;
    if (kc < HKD / 32 - 1) asm volatile("s_waitcnt vmcnt(6)" ::: "memory");
    else                   asm volatile("s_waitcnt vmcnt(0)" ::: "memory");
    __syncthreads();
    short8 a[4], b[4];
    #pragma unroll
    for (int i = 0; i < 4; ++i)
      a[i] = *(const short8*)&As[cur][(wr + i * 16 + cl) * 32 + ((quad ^ (cl & 3)) * 8)];
    #pragma unroll
    for (int j = 0; j < 4; ++j)
      b[j] = *(const short8*)&Bs[cur][(j * 16 + cl) * 32 + ((quad ^ (cl & 3)) * 8)];
    #pragma unroll
    for (int i = 0; i < 4; ++i)
      #pragma unroll
      for (int j = 0; j < 4; ++j)
        acc[i][j] = mfma16(a[i], b[j], acc[i][j]);
    __syncthreads();
    if (kc + 2 < HKD / 32) stage(kc + 2, cur);
  }
  #pragma unroll
  for (int j = 0; j < 4; ++j) {
    float bj = bo[n0 + j * 16 + cl];
    #pragma unroll
    for (int i = 0; i < 4; ++i)
      #pragma unroll
      for (int r = 0; r < 4; ++r) {
        int token = m0 + wr + i * 16 + quad * 4 + r;
        out[token * DM + n0 + j * 16 + cl] = acc[i][j][r] + bj;
      }
  }
}

extern "C" void kernel_launch(void* const* d_in, const int* in_sizes, int n_in,
                              void* d_out, int out_size, void* d_ws, size_t ws_size,
                              hipStream_t stream) {
  const float* x  = (const float*)d_in[0];
  const float* Wq = (const float*)d_in[1];
  const float* bq = (const float*)d_in[2];
  const float* Wk = (const float*)d_in[3];
  const float* bk = (const float*)d_in[4];
  const float* Wv = (const float*)d_in[5];
  const float* bv = (const float*)d_in[6];
  const float* Wo = (const float*)d_in[7];
  const float* bo = (const float*)d_in[8];
  float* out = (float*)d_out;
  char* ws = (char*)d_ws;
  unsigned short* xb  = (unsigned short*)(ws);                       // 8 MiB
  unsigned short* wqt = (unsigned short*)(ws + (8ull  << 20));       // 2 MiB
  unsigned short* wkt = (unsigned short*)(ws + (10ull << 20));       // 2 MiB
  unsigned short* wvt = (unsigned short*)(ws + (12ull << 20));       // 2 MiB
  unsigned short* wot = (unsigned short*)(ws + (14ull << 20));       // 2 MiB
  unsigned short* qb  = (unsigned short*)(ws + (16ull << 20));       // 8 MiB
  unsigned short* kbf = (unsigned short*)(ws + (24ull << 20));       // 8 MiB
  unsigned short* vt  = (unsigned short*)(ws + (40ull << 20));       // 8 MiB
  unsigned short* ao  = (unsigned short*)(ws + (48ull << 20));       // 8 MiB

  hipLaunchKernelGGL(prep_kernel, dim3(NT * DM / 1024 + 1024), dim3(256), 0, stream,
                     x, Wq, Wk, Wv, Wo, xb, wqt, wkt, wvt, wot);
  hipLaunchKernelGGL(gemm_qkv_kernel, dim3(NT / 128, HKD / 128, 3), dim3(256), 0, stream,
                     xb, wqt, wkt, wvt, bq, bk, bv, qb, kbf, vt);
  hipLaunchKernelGGL(attn_kernel, dim3(SS / 64, NH, BB), dim3(256), 0, stream, qb, kbf, vt, ao);
  hipLaunchKernelGGL(gemm_out_kernel, dim3(NT / 128, DM / 64), dim3(128), 0, stream, ao, wot, bo, out);
}

// Round 9
// 201.022 us; speedup vs baseline: 1.0709x; 1.0699x over previous
//
#include <hip/hip_runtime.h>

// MHA forward, B=2, S=2048, D=1024, H=16, K=64, fp32 in/out, bf16 MFMA internally.
// R9: attn 8 waves/WG x 16 q-rows (128 q-rows/WG, K/V tile shared by 8 waves,
// 16 waves/CU); raw asm s_barrier (no compiler vmcnt(0) drain) in all K-loops;
// gemm_out 256x64 tile / 4 waves / 256 thr (8 waves/CU, shared B tile).

#define NH 16
#define KS 64
#define DM 1024
#define BB 2
#define SS 2048
#define NT (BB*SS)   // 4096 tokens
#define HKD 1024     // NH*KS
#define L2E 1.44269504088896340736f

typedef __attribute__((ext_vector_type(4))) float floatx4;
typedef __attribute__((ext_vector_type(8))) short short8;

#define BAR() asm volatile("s_barrier" ::: "memory")

__device__ __forceinline__ unsigned short f2b(float f) {
  unsigned u = __builtin_bit_cast(unsigned, f);
  u = (u + 0x7fffu + ((u >> 16) & 1u)) >> 16;
  return (unsigned short)u;
}

__device__ __forceinline__ floatx4 mfma16(short8 a, short8 b, floatx4 c) {
  return __builtin_amdgcn_mfma_f32_16x16x32_bf16(a, b, c, 0, 0, 0);
}

// async global->LDS, 16B per lane. LDS dest must be wave-uniform base + lane*16.
__device__ __forceinline__ void async16(const void* g, void* l) {
  __builtin_amdgcn_global_load_lds(
      (const __attribute__((address_space(1))) unsigned int*)g,
      (__attribute__((address_space(3))) unsigned int*)l, 16, 0, 0);
}

// ------ prep: cast x (f32->bf16) + transpose+cast all W, one launch ------
__global__ __launch_bounds__(256) void prep_kernel(
    const float* __restrict__ x,
    const float* __restrict__ Wq, const float* __restrict__ Wk,
    const float* __restrict__ Wv, const float* __restrict__ Wo,
    unsigned short* __restrict__ xb,
    unsigned short* __restrict__ wqt, unsigned short* __restrict__ wkt,
    unsigned short* __restrict__ wvt, unsigned short* __restrict__ wot) {
  int bid = blockIdx.x;
  if (bid < NT * DM / 1024) {
    int i = (bid * 256 + threadIdx.x) * 4;
    float4 v = *(const float4*)(x + i);
    ushort4 o;
    o.x = f2b(v.x); o.y = f2b(v.y); o.z = f2b(v.z); o.w = f2b(v.w);
    *(ushort4*)(xb + i) = o;
    return;
  }
  int b2 = bid - NT * DM / 1024;
  int z = b2 >> 8;
  const float* W; unsigned short* Wt;
  if (z == 0)      { W = Wq; Wt = wqt; }
  else if (z == 1) { W = Wk; Wt = wkt; }
  else if (z == 2) { W = Wv; Wt = wvt; }
  else             { W = Wo; Wt = wot; }
  __shared__ __align__(16) unsigned short tile[64][80];
  int k0 = (b2 & 15) * 64, n0 = ((b2 >> 4) & 15) * 64;
  int t = threadIdx.x;
  int c0 = (t & 15) * 4, r = t >> 4;
  #pragma unroll
  for (int p = 0; p < 4; ++p) {
    int rr = r + p * 16;
    float4 v = *(const float4*)(W + (k0 + rr) * DM + n0 + c0);
    tile[c0 + 0][rr] = f2b(v.x);
    tile[c0 + 1][rr] = f2b(v.y);
    tile[c0 + 2][rr] = f2b(v.z);
    tile[c0 + 3][rr] = f2b(v.w);
  }
  __syncthreads();
  int cc0 = (t & 7) * 8, rn = t >> 3;
  #pragma unroll
  for (int p = 0; p < 2; ++p) {
    int nn = rn + p * 32;
    *(short8*)(Wt + (n0 + nn) * DM + k0 + cc0) = *(const short8*)(&tile[nn][cc0]);
  }
}

// ---- QKV GEMM: 128x128 tile, 4 waves, BK=32 dbuf + vmcnt(4) prefetch ----
__global__ __launch_bounds__(256) void gemm_qkv_kernel(
    const unsigned short* __restrict__ xb,
    const unsigned short* __restrict__ wqt, const unsigned short* __restrict__ wkt,
    const unsigned short* __restrict__ wvt,
    const float* __restrict__ bq, const float* __restrict__ bk, const float* __restrict__ bv,
    unsigned short* __restrict__ qb, unsigned short* __restrict__ kbuf,
    unsigned short* __restrict__ vt) {
  __shared__ __align__(16) unsigned short smem[18432];
  const unsigned short* Bt; const float* bias; float scale; int zid = blockIdx.z;
  if (zid == 0)      { Bt = wqt; bias = bq; scale = 0.125f * L2E; }
  else if (zid == 1) { Bt = wkt; bias = bk; scale = 1.0f; }
  else               { Bt = wvt; bias = bv; scale = 1.0f; }
  int m0 = blockIdx.x * 128, n0 = blockIdx.y * 128;
  int t = threadIdx.x, w = t >> 6, lane = t & 63, cl = lane & 15, quad = lane >> 4;
  int wr = (w >> 1) * 64, wc = (w & 1) * 64;
  floatx4 acc[4][4];
  #pragma unroll
  for (int i = 0; i < 4; ++i)
    #pragma unroll
    for (int j = 0; j < 4; ++j)
      acc[i][j] = floatx4{0.f, 0.f, 0.f, 0.f};

  auto stage = [&](int kc, int buf) {
    #pragma unroll
    for (int i = 0; i < 2; ++i) {
      int c = i * 256 + t;
      int row = c >> 2, col = (c & 3) ^ (row & 3);
      async16(xb + (m0 + row) * DM + kc * 32 + col * 8, &smem[buf * 4096 + c * 8]);
      async16(Bt + (n0 + row) * DM + kc * 32 + col * 8, &smem[8192 + buf * 4096 + c * 8]);
    }
  };
  stage(0, 0);
  stage(1, 1);

  for (int kc = 0; kc < DM / 32; ++kc) {
    int cur = kc & 1;
    if (kc < DM / 32 - 1) asm volatile("s_waitcnt vmcnt(4)" ::: "memory");
    else                  asm volatile("s_waitcnt vmcnt(0)" ::: "memory");
    BAR();
    const unsigned short* Ac = &smem[cur * 4096];
    const unsigned short* Bc = &smem[8192 + cur * 4096];
    short8 a[4], b[4];
    #pragma unroll
    for (int i = 0; i < 4; ++i)
      a[i] = *(const short8*)&Ac[(wr + i * 16 + cl) * 32 + ((quad ^ (cl & 3)) * 8)];
    #pragma unroll
    for (int j = 0; j < 4; ++j)
      b[j] = *(const short8*)&Bc[(wc + j * 16 + cl) * 32 + ((quad ^ (cl & 3)) * 8)];
    #pragma unroll
    for (int i = 0; i < 4; ++i)
      #pragma unroll
      for (int j = 0; j < 4; ++j)
        acc[i][j] = mfma16(a[i], b[j], acc[i][j]);
    BAR();
    if (kc + 2 < DM / 32) stage(kc + 2, cur);
  }
  __syncthreads();

  int h = (n0 + wc) >> 6;
  if (zid < 2) {
    unsigned short* dst = (zid == 0) ? qb : kbuf;
    #pragma unroll
    for (int j = 0; j < 4; ++j) {
      float bj = bias[n0 + wc + j * 16 + cl];
      int kd = j * 16 + cl;
      #pragma unroll
      for (int i = 0; i < 4; ++i)
        #pragma unroll
        for (int r = 0; r < 4; ++r) {
          int token = m0 + wr + i * 16 + quad * 4 + r;
          int bz = token >> 11, s = token & (SS - 1);
          float val = (acc[i][j][r] + bj) * scale;
          dst[(((bz * NH + h) * SS + s) << 6) + kd] = f2b(val);
        }
    }
  } else {
    unsigned short* tr = &smem[w * 4608];
    #pragma unroll
    for (int j = 0; j < 4; ++j) {
      float bj = bias[n0 + wc + j * 16 + cl];
      #pragma unroll
      for (int i = 0; i < 4; ++i) {
        unsigned short b0 = f2b(acc[i][j][0] + bj), b1 = f2b(acc[i][j][1] + bj);
        unsigned short b2 = f2b(acc[i][j][2] + bj), b3 = f2b(acc[i][j][3] + bj);
        uint2 pk;
        pk.x = (unsigned)b0 | ((unsigned)b1 << 16);
        pk.y = (unsigned)b2 | ((unsigned)b3 << 16);
        *(uint2*)&tr[(j * 16 + cl) * 72 + i * 16 + quad * 4] = pk;
      }
    }
    asm volatile("s_waitcnt lgkmcnt(0)" ::: "memory");
    int tokbase = m0 + wr;
    int bz = tokbase >> 11, s0 = tokbase & (SS - 1);
    unsigned short* vdst = vt + (((bz * NH + h) * KS) * SS) + s0;
    #pragma unroll
    for (int p = 0; p < 8; ++p) {
      int row = p * 8 + (lane >> 3);
      int tk = (lane & 7) * 8;
      short8 vv = *(const short8*)&tr[row * 72 + tk];
      *(short8*)(vdst + row * SS + tk) = vv;
    }
  }
}

// ---- attention: 8 waves x 16 q-rows (128/WG), S^T/O^T, shared dbuf K/V, vmcnt(2) ----
// l via ones-MFMA on the same P^T fragments (consistent by construction).
__global__ __launch_bounds__(512) void attn_kernel(
    const unsigned short* __restrict__ Q, const unsigned short* __restrict__ Kb,
    const unsigned short* __restrict__ Vt, unsigned short* __restrict__ AO) {
  __shared__ __align__(16) unsigned short Ks[2][4096], Vs[2][4096]; // 64x64 swizzled dbuf (32 KB)
  __shared__ __align__(16) unsigned short Ps[8][1024];              // per-wave P^T, swizzled (16 KB)
  int t = threadIdx.x, w = t >> 6, lane = t & 63, cl = lane & 15, quad = lane >> 4;
  int clm = cl & 7;
  int h = blockIdx.y, bz = blockIdx.z, bh = bz * NH + h;
  int q0 = blockIdx.x * 128 + w * 16;
  const unsigned short* Qp = Q + (bh * SS + q0) * KS;
  const unsigned short* Kp = Kb + bh * SS * KS;
  const unsigned short* Vp = Vt + bh * KS * SS;
  unsigned short* p_w = Ps[w];

  short8 qa[2];
  #pragma unroll
  for (int c = 0; c < 2; ++c)
    qa[c] = *(const short8*)(Qp + cl * KS + c * 32 + quad * 8);

  short8 ones;
  #pragma unroll
  for (int j = 0; j < 8; ++j) ones[j] = (short)0x3f80; // bf16 1.0

  floatx4 lacc = {0.f, 0.f, 0.f, 0.f};
  floatx4 oa[4];
  #pragma unroll
  for (int j = 0; j < 4; ++j) oa[j] = floatx4{0.f, 0.f, 0.f, 0.f};

  // stage one 64-key tile: 1 K-segment + 1 V-segment per thread (2 vm ops)
  auto stage = [&](int tile, int buf) {
    int row = t >> 3, col8 = (t & 7) ^ (row & 7);
    async16(Kp + (tile * 64 + row) * KS + col8 * 8, &Ks[buf][t * 8]);
    async16(Vp + row * SS + tile * 64 + col8 * 8, &Vs[buf][t * 8]);
  };
  stage(0, 0);
  stage(1, 1);

  const int NTILES = SS / 64;
  for (int it = 0; it < NTILES; ++it) {
    int cur = it & 1;
    if (it < NTILES - 1) asm volatile("s_waitcnt vmcnt(2)" ::: "memory");
    else                 asm volatile("s_waitcnt vmcnt(0)" ::: "memory");
    BAR();

    floatx4 s[4];
    #pragma unroll
    for (int kt = 0; kt < 4; ++kt) {
      short8 kb0 = *(const short8*)&Ks[cur][(kt * 16 + cl) * 64 + ((quad ^ clm) * 8)];
      short8 kb1 = *(const short8*)&Ks[cur][(kt * 16 + cl) * 64 + (((4 + quad) ^ clm) * 8)];
      floatx4 z = {0.f, 0.f, 0.f, 0.f};
      s[kt] = mfma16(kb1, qa[1], mfma16(kb0, qa[0], z));
    }
    #pragma unroll
    for (int kt = 0; kt < 4; ++kt) {
      unsigned u[4];
      #pragma unroll
      for (int r = 0; r < 4; ++r)
        u[r] = __builtin_bit_cast(unsigned, __builtin_amdgcn_exp2f(s[kt][r]));
      uint2 pk;
      pk.x = __builtin_amdgcn_perm(u[1], u[0], 0x07060302);
      pk.y = __builtin_amdgcn_perm(u[3], u[2], 0x07060302);
      int off = cl * 64 + (((kt * 2 + (quad >> 1)) ^ clm) * 8) + (quad & 1) * 4;
      *(uint2*)(p_w + off) = pk;
    }
    asm volatile("s_waitcnt lgkmcnt(0)" ::: "memory");
    short8 pa[2];
    #pragma unroll
    for (int c = 0; c < 2; ++c)
      pa[c] = *(const short8*)(p_w + cl * 64 + (((c * 4 + quad) ^ clm) * 8));
    lacc = mfma16(ones, pa[1], mfma16(ones, pa[0], lacc));
    #pragma unroll
    for (int j = 0; j < 4; ++j) {
      short8 vb0 = *(const short8*)&Vs[cur][(j * 16 + cl) * 64 + ((quad ^ clm) * 8)];
      short8 vb1 = *(const short8*)&Vs[cur][(j * 16 + cl) * 64 + (((4 + quad) ^ clm) * 8)];
      oa[j] = mfma16(vb1, pa[1], mfma16(vb0, pa[0], oa[j]));
    }
    BAR();
    if (it + 2 < NTILES) stage(it + 2, cur);
  }

  float inv = 1.0f / lacc[0];
  unsigned short* aop = AO + (bz * SS + q0 + cl) * DM + h * KS + quad * 4;
  #pragma unroll
  for (int j = 0; j < 4; ++j) {
    unsigned short b0 = f2b(oa[j][0] * inv), b1 = f2b(oa[j][1] * inv);
    unsigned short b2 = f2b(oa[j][2] * inv), b3 = f2b(oa[j][3] * inv);
    uint2 pk;
    pk.x = (unsigned)b0 | ((unsigned)b1 << 16);
    pk.y = (unsigned)b2 | ((unsigned)b3 << 16);
    *(uint2*)(aop + j * 16) = pk;
  }
}

// ---- output GEMM: 256x64 tile, 4 waves, BK=32 dbuf + vmcnt(5), f32 out + bias ----
// Shared B tile across 4 waves; 256 WG x 4 waves = 8 waves/CU.
__global__ __launch_bounds__(256) void gemm_out_kernel(
    const unsigned short* __restrict__ ao, const unsigned short* __restrict__ wot,
    const float* __restrict__ bo, float* __restrict__ out) {
  __shared__ __align__(16) unsigned short As[2][8192], Bs[2][2048]; // 40 KB
  int m0 = blockIdx.x * 256, n0 = blockIdx.y * 64;
  int t = threadIdx.x, w = t >> 6, lane = t & 63, cl = lane & 15, quad = lane >> 4;
  int wr = w * 64;
  floatx4 acc[4][4];
  #pragma unroll
  for (int i = 0; i < 4; ++i)
    #pragma unroll
    for (int j = 0; j < 4; ++j)
      acc[i][j] = floatx4{0.f, 0.f, 0.f, 0.f};

  auto stage = [&](int kc, int buf) {
    #pragma unroll
    for (int i = 0; i < 4; ++i) {
      int c = i * 256 + t;                       // 0..1023 -> 256 rows x 4 col-blocks
      int row = c >> 2, col = (c & 3) ^ (row & 3);
      async16(ao + (m0 + row) * HKD + kc * 32 + col * 8, &As[buf][c * 8]);
    }
    {
      int c = t;                                 // 0..255 -> 64 rows x 4 col-blocks
      int row = c >> 2, col = (c & 3) ^ (row & 3);
      async16(wot + (n0 + row) * HKD + kc * 32 + col * 8, &Bs[buf][c * 8]);
    }
  };
  stage(0, 0);
  stage(1, 1);

  for (int kc = 0; kc < HKD / 32; ++kc) {
    int cur = kc & 1;
    if (kc < HKD / 32 - 1) asm volatile("s_waitcnt vmcnt(5)" ::: "memory");
    else                   asm volatile("s_waitcnt vmcnt(0)" ::: "memory");
    BAR();
    short8 a[4], b[4];
    #pragma unroll
    for (int i = 0; i < 4; ++i)
      a[i] = *(const short8*)&As[cur][(wr + i * 16 + cl) * 32 + ((quad ^ (cl & 3)) * 8)];
    #pragma unroll
    for (int j = 0; j < 4; ++j)
      b[j] = *(const short8*)&Bs[cur][(j * 16 + cl) * 32 + ((quad ^ (cl & 3)) * 8)];
    #pragma unroll
    for (int i = 0; i < 4; ++i)
      #pragma unroll
      for (int j = 0; j < 4; ++j)
        acc[i][j] = mfma16(a[i], b[j], acc[i][j]);
    BAR();
    if (kc + 2 < HKD / 32) stage(kc + 2, cur);
  }
  #pragma unroll
  for (int j = 0; j < 4; ++j) {
    float bj = bo[n0 + j * 16 + cl];
    #pragma unroll
    for (int i = 0; i < 4; ++i)
      #pragma unroll
      for (int r = 0; r < 4; ++r) {
        int token = m0 + wr + i * 16 + quad * 4 + r;
        out[token * DM + n0 + j * 16 + cl] = acc[i][j][r] + bj;
      }
  }
}

extern "C" void kernel_launch(void* const* d_in, const int* in_sizes, int n_in,
                              void* d_out, int out_size, void* d_ws, size_t ws_size,
                              hipStream_t stream) {
  const float* x  = (const float*)d_in[0];
  const float* Wq = (const float*)d_in[1];
  const float* bq = (const float*)d_in[2];
  const float* Wk = (const float*)d_in[3];
  const float* bk = (const float*)d_in[4];
  const float* Wv = (const float*)d_in[5];
  const float* bv = (const float*)d_in[6];
  const float* Wo = (const float*)d_in[7];
  const float* bo = (const float*)d_in[8];
  float* out = (float*)d_out;
  char* ws = (char*)d_ws;
  unsigned short* xb  = (unsigned short*)(ws);                       // 8 MiB
  unsigned short* wqt = (unsigned short*)(ws + (8ull  << 20));       // 2 MiB
  unsigned short* wkt = (unsigned short*)(ws + (10ull << 20));       // 2 MiB
  unsigned short* wvt = (unsigned short*)(ws + (12ull << 20));       // 2 MiB
  unsigned short* wot = (unsigned short*)(ws + (14ull << 20));       // 2 MiB
  unsigned short* qb  = (unsigned short*)(ws + (16ull << 20));       // 8 MiB
  unsigned short* kbf = (unsigned short*)(ws + (24ull << 20));       // 8 MiB
  unsigned short* vt  = (unsigned short*)(ws + (40ull << 20));       // 8 MiB
  unsigned short* ao  = (unsigned short*)(ws + (48ull << 20));       // 8 MiB

  hipLaunchKernelGGL(prep_kernel, dim3(NT * DM / 1024 + 1024), dim3(256), 0, stream,
                     x, Wq, Wk, Wv, Wo, xb, wqt, wkt, wvt, wot);
  hipLaunchKernelGGL(gemm_qkv_kernel, dim3(NT / 128, HKD / 128, 3), dim3(256), 0, stream,
                     xb, wqt, wkt, wvt, bq, bk, bv, qb, kbf, vt);
  hipLaunchKernelGGL(attn_kernel, dim3(SS / 128, NH, BB), dim3(512), 0, stream, qb, kbf, vt, ao);
  hipLaunchKernelGGL(gemm_out_kernel, dim3(NT / 256, DM / 64), dim3(256), 0, stream, ao, wot, bo, out);
}